// Round 1
// baseline (1707.793 us; speedup 1.0000x reference)
//
#include <hip/hip_runtime.h>
#include <hip/hip_bf16.h>

#define T_STEPS 1024
#define BATCH   64
#define INP_    512
#define HS_     1024
#define OUT_    512
#define MROWS   (T_STEPS*BATCH)   // 65536

typedef __bf16 bf16;
typedef bf16  bf16x8 __attribute__((ext_vector_type(8)));
typedef bf16  bf16x4 __attribute__((ext_vector_type(4)));
typedef float f32x4  __attribute__((ext_vector_type(4)));

__device__ __forceinline__ void gload_lds16(const bf16* g, bf16* l) {
  __builtin_amdgcn_global_load_lds(
      (const __attribute__((address_space(1))) void*)g,
      (__attribute__((address_space(3))) void*)l,
      16, 0, 0);
}

// ---------------- fp32 -> bf16 conversion (vectorized x4) ----------------
__global__ void f2b(const float* __restrict__ in, bf16* __restrict__ out, int n4) {
  int stride = gridDim.x * blockDim.x;
  for (int i = blockIdx.x * blockDim.x + threadIdx.x; i < n4; i += stride) {
    float4 v = ((const float4*)in)[i];
    bf16x4 o;
    o[0] = (bf16)v.x; o[1] = (bf16)v.y; o[2] = (bf16)v.z; o[3] = (bf16)v.w;
    ((bf16x4*)out)[i] = o;
  }
}

// ---------------- GEMM: C[M,N] = A[M,K] * Bw[N,K]^T  (+ epilogue) ----------------
// MODE 0: C = acc + bias                      (bf16 out)
// MODE 1: a = sigmoid(acc+bias); C = a (bf16); Gate = a > thr
// MODE 2: a = sigmoid(acc+bias);              Gate = a > thr   (no C)
template<int MODE>
__global__ __launch_bounds__(256, 2)
void gemm_bt(const bf16* __restrict__ A, const bf16* __restrict__ Bw,
             const float* __restrict__ bias, const float* __restrict__ thr,
             bf16* __restrict__ C, unsigned char* __restrict__ Gate,
             int N, int K, int nbn) {
  __shared__ __align__(16) bf16 lds[2][2][128 * 32];
  const int tid  = threadIdx.x;
  const int wave = tid >> 6, lane = tid & 63;
  const int br = blockIdx.x / nbn, bc = blockIdx.x % nbn;
  const int wr = wave >> 1, wc = wave & 1;

  const bf16* Ag = A  + (size_t)br * 128 * K;
  const bf16* Bg = Bw + (size_t)bc * 128 * K;

  f32x4 acc[4][4];
  #pragma unroll
  for (int m = 0; m < 4; ++m)
    #pragma unroll
    for (int n = 0; n < 4; ++n) {
      f32x4 z = {0.f, 0.f, 0.f, 0.f};
      acc[m][n] = z;
    }

  const int nk = K >> 5;   // BK = 32
  int cur = 0;

  // prologue: stage k-step 0 into buf 0
  #pragma unroll
  for (int i = 0; i < 2; ++i) {
    int cg = (i * 4 + wave) * 64;          // wave-uniform chunk-group base
    int c  = cg + lane;
    int row = c >> 2, kc = c & 3;
    gload_lds16(Ag + (size_t)row * K + kc * 8, &lds[0][0][0] + cg * 8);
    gload_lds16(Bg + (size_t)row * K + kc * 8, &lds[0][1][0] + cg * 8);
  }
  __syncthreads();

  for (int ks = 0; ks < nk; ++ks) {
    if (ks + 1 < nk) {                     // prefetch next k-step into other buffer
      const bf16* Agk = Ag + (ks + 1) * 32;
      const bf16* Bgk = Bg + (ks + 1) * 32;
      #pragma unroll
      for (int i = 0; i < 2; ++i) {
        int cg = (i * 4 + wave) * 64;
        int c  = cg + lane;
        int row = c >> 2, kc = c & 3;
        gload_lds16(Agk + (size_t)row * K + kc * 8, &lds[cur ^ 1][0][0] + cg * 8);
        gload_lds16(Bgk + (size_t)row * K + kc * 8, &lds[cur ^ 1][1][0] + cg * 8);
      }
    }
    const bf16* lA = &lds[cur][0][0] + (wr * 64 + (lane & 15)) * 32 + (lane >> 4) * 8;
    const bf16* lB = &lds[cur][1][0] + (wc * 64 + (lane & 15)) * 32 + (lane >> 4) * 8;
    bf16x8 af[4], bfr[4];
    #pragma unroll
    for (int m = 0; m < 4; ++m) af[m]  = *(const bf16x8*)(lA + m * 512);
    #pragma unroll
    for (int n = 0; n < 4; ++n) bfr[n] = *(const bf16x8*)(lB + n * 512);
    #pragma unroll
    for (int m = 0; m < 4; ++m)
      #pragma unroll
      for (int n = 0; n < 4; ++n)
        acc[m][n] = __builtin_amdgcn_mfma_f32_16x16x32_bf16(af[m], bfr[n], acc[m][n], 0, 0, 0);
    __syncthreads();
    cur ^= 1;
  }

  // epilogue: C/D layout col = lane&15, row = (lane>>4)*4 + reg
  const int rowbase0 = br * 128 + wr * 64 + ((lane >> 4) << 2);
  const int colbase  = bc * 128 + wc * 64 + (lane & 15);
  #pragma unroll
  for (int n = 0; n < 4; ++n) {
    int col = colbase + n * 16;
    float bv = bias[col];
    float tv = 0.f;
    if (MODE >= 1) tv = thr[col];
    #pragma unroll
    for (int m = 0; m < 4; ++m) {
      int row = rowbase0 + m * 16;
      #pragma unroll
      for (int j = 0; j < 4; ++j) {
        float v = acc[m][n][j] + bv;
        size_t off = (size_t)(row + j) * N + col;
        if (MODE == 0) {
          C[off] = (bf16)v;
        } else {
          float a = 1.f / (1.f + __expf(-v));
          if (MODE == 1) { C[off] = (bf16)a; Gate[off] = (a > tv) ? 1 : 0; }
          else           { Gate[off] = (a > tv) ? 1 : 0; }
        }
      }
    }
  }
}

// ---------------- recurrence 1: h1 = h1*g1*dr1 + z1 ; an1 = tanh(h1) (in place) ----
__global__ __launch_bounds__(256)
void rec1(const bf16* Z, bf16* AN, const unsigned char* __restrict__ G,
          const float* __restrict__ dr) {
  int e = blockIdx.x * 256 + threadIdx.x;          // e = b*HS + h
  int h = e & (HS_ - 1);
  float d = dr[h];
  float hs = 0.f;
  size_t idx = (size_t)e;
  #pragma unroll 8
  for (int t = 0; t < T_STEPS; ++t, idx += (size_t)BATCH * HS_) {
    float z  = (float)Z[idx];
    float al = G[idx] ? d : 0.f;
    hs = hs * al + z;
    AN[idx] = (bf16)tanhf(hs);
  }
}

// ---------------- recurrence 2: only final h2 needed --------------------------------
__global__ __launch_bounds__(256)
void rec2(const bf16* __restrict__ Z, const unsigned char* __restrict__ G,
          const float* __restrict__ dr, float* __restrict__ an2) {
  int e = blockIdx.x * 256 + threadIdx.x;
  int h = e & (HS_ - 1);
  float d = dr[h];
  float hs = 0.f;
  size_t idx = (size_t)e;
  #pragma unroll 8
  for (int t = 0; t < T_STEPS; ++t, idx += (size_t)BATCH * HS_) {
    float z  = (float)Z[idx];
    float al = G[idx] ? d : 0.f;
    hs = hs * al + z;
  }
  an2[e] = tanhf(hs);
}

// ---------------- readout: out[b,o] = sum_h an2[b,h] * W3[o,h] + b3[o] (fp32) -------
__global__ __launch_bounds__(256)
void readout(const float* __restrict__ an2, const float* __restrict__ W3,
             const float* __restrict__ b3, float* __restrict__ out) {
  int idx = blockIdx.x * 256 + threadIdx.x;        // 64*512 threads
  int b = idx >> 9, o = idx & 511;
  const float4* a = (const float4*)(an2 + (size_t)b * HS_);
  const float4* w = (const float4*)(W3 + (size_t)o * HS_);
  float s = 0.f;
  #pragma unroll 4
  for (int k = 0; k < HS_ / 4; ++k) {
    float4 x = a[k], y = w[k];
    s += x.x * y.x + x.y * y.y + x.z * y.z + x.w * y.w;
  }
  out[idx] = s + b3[o];
}

extern "C" void kernel_launch(void* const* d_in, const int* in_sizes, int n_in,
                              void* d_out, int out_size, void* d_ws, size_t ws_size,
                              hipStream_t stream) {
  const float* data = (const float*)d_in[0];
  const float* W1   = (const float*)d_in[1];
  const float* b1   = (const float*)d_in[2];
  const float* Wi1  = (const float*)d_in[3];
  const float* bi1  = (const float*)d_in[4];
  const float* t1   = (const float*)d_in[5];
  const float* dr1  = (const float*)d_in[6];
  const float* W2   = (const float*)d_in[7];
  const float* b2   = (const float*)d_in[8];
  const float* Wi2  = (const float*)d_in[9];
  const float* bi2  = (const float*)d_in[10];
  const float* t2   = (const float*)d_in[11];
  const float* dr2  = (const float*)d_in[12];
  const float* W3   = (const float*)d_in[13];
  const float* b3   = (const float*)d_in[14];

  char* p = (char*)d_ws;
  bf16* Xbf  = (bf16*)p; p += (size_t)MROWS * INP_ * 2;   // 67 MB
  bf16* bufA = (bf16*)p; p += (size_t)MROWS * HS_ * 2;    // 134 MB  Z1 -> AN1 (in place)
  bf16* bufB = (bf16*)p; p += (size_t)MROWS * HS_ * 2;    // 134 MB  A1 -> Z2 (reused)
  unsigned char* G1 = (unsigned char*)p; p += (size_t)MROWS * HS_;  // 67 MB
  unsigned char* G2 = (unsigned char*)p; p += (size_t)MROWS * HS_;  // 67 MB
  bf16* W1b  = (bf16*)p; p += (size_t)HS_ * INP_ * 2;
  bf16* Wi1b = (bf16*)p; p += (size_t)HS_ * INP_ * 2;
  bf16* W2b  = (bf16*)p; p += (size_t)HS_ * HS_ * 2;
  bf16* Wi2b = (bf16*)p; p += (size_t)HS_ * HS_ * 2;
  float* an2 = (float*)p; p += (size_t)BATCH * HS_ * 4;

  // convert inputs/weights to bf16
  f2b<<<2048, 256, 0, stream>>>(data, Xbf, MROWS * INP_ / 4);
  f2b<<<512,  256, 0, stream>>>(W1,  W1b,  HS_ * INP_ / 4);
  f2b<<<512,  256, 0, stream>>>(Wi1, Wi1b, HS_ * INP_ / 4);
  f2b<<<1024, 256, 0, stream>>>(W2,  W2b,  HS_ * HS_ / 4);
  f2b<<<1024, 256, 0, stream>>>(Wi2, Wi2b, HS_ * HS_ / 4);

  const int nbn = HS_ / 128;                 // 8
  dim3 gg((MROWS / 128) * nbn);              // 4096 blocks

  // Z1 = X@W1^T + b1
  gemm_bt<0><<<gg, 256, 0, stream>>>(Xbf, W1b, b1, nullptr, bufA, nullptr, HS_, INP_, nbn);
  // A1 = sigmoid(X@Wi1^T + bi1), G1 = A1 > t1
  gemm_bt<1><<<gg, 256, 0, stream>>>(Xbf, Wi1b, bi1, t1, bufB, G1, HS_, INP_, nbn);
  // G2 = sigmoid(A1@Wi2^T + bi2) > t2
  gemm_bt<2><<<gg, 256, 0, stream>>>(bufB, Wi2b, bi2, t2, nullptr, G2, HS_, HS_, nbn);
  // h1 scan + tanh -> AN1 (in place over Z1)
  rec1<<<BATCH * HS_ / 256, 256, 0, stream>>>(bufA, bufA, G1, dr1);
  // Z2 = AN1@W2^T + b2   (overwrites A1 buffer, A1 is dead after GEMM3)
  gemm_bt<0><<<gg, 256, 0, stream>>>(bufA, W2b, b2, nullptr, bufB, nullptr, HS_, HS_, nbn);
  // h2 scan -> an2 = tanh(h2_final)
  rec2<<<BATCH * HS_ / 256, 256, 0, stream>>>(bufB, G2, dr2, an2);
  // out = an2 @ W3^T + b3
  readout<<<BATCH * OUT_ / 256, 256, 0, stream>>>(an2, W3, b3, (float*)d_out);
}

// Round 3
// 1055.457 us; speedup vs baseline: 1.6181x; 1.6181x over previous
//
#include <hip/hip_runtime.h>
#include <hip/hip_bf16.h>

#define T_STEPS 1024
#define BATCH   64
#define INP_    512
#define HS_     1024
#define OUT_    512
#define MROWS   (T_STEPS*BATCH)   // 65536
#define NE      (BATCH*HS_)       // 65536 lanes in the recurrence
#define CH      16                // scan chunks
#define CL      (T_STEPS/CH)      // 64 steps per chunk

typedef __bf16 bf16;
typedef bf16  bf16x8 __attribute__((ext_vector_type(8)));
typedef bf16  bf16x4 __attribute__((ext_vector_type(4)));
typedef bf16  bf16x2 __attribute__((ext_vector_type(2)));
typedef float f32x4  __attribute__((ext_vector_type(4)));

__device__ __forceinline__ void gload_lds16(const bf16* g, bf16* l) {
  __builtin_amdgcn_global_load_lds(
      (const __attribute__((address_space(1))) void*)g,
      (__attribute__((address_space(3))) void*)l,
      16, 0, 0);
}

__device__ __forceinline__ float ftanh(float x) {
  float e = __expf(2.f * x);
  return 1.f - 2.f / (e + 1.f);
}

// ---------------- fp32 -> bf16 conversion (vectorized x4) ----------------
__global__ void f2b(const float* __restrict__ in, bf16* __restrict__ out, int n4) {
  int stride = gridDim.x * blockDim.x;
  for (int i = blockIdx.x * blockDim.x + threadIdx.x; i < n4; i += stride) {
    float4 v = ((const float4*)in)[i];
    bf16x4 o;
    o[0] = (bf16)v.x; o[1] = (bf16)v.y; o[2] = (bf16)v.z; o[3] = (bf16)v.w;
    ((bf16x4*)out)[i] = o;
  }
}

// ---------------- GEMM: C[M,N] = A[M,K] * Bw[N,K]^T  (+ epilogue) ----------------
// MODE 0: C = acc + bias                      (bf16 out)
// MODE 1: a = sigmoid(acc+bias); C = a (bf16); Gate = a > thr
// MODE 2: a = sigmoid(acc+bias);              Gate = a > thr   (no C)
template<int MODE>
__global__ __launch_bounds__(256, 2)
void gemm_bt(const bf16* __restrict__ A, const bf16* __restrict__ Bw,
             const float* __restrict__ bias, const float* __restrict__ thr,
             bf16* __restrict__ C, unsigned char* __restrict__ Gate,
             int N, int K, int nbn) {
  __shared__ __align__(16) bf16 lds[2][2][128 * 32];
  const int tid  = threadIdx.x;
  const int wave = tid >> 6, lane = tid & 63;
  const int br = blockIdx.x / nbn, bc = blockIdx.x % nbn;
  const int wr = wave >> 1, wc = wave & 1;

  const bf16* Ag = A  + (size_t)br * 128 * K;
  const bf16* Bg = Bw + (size_t)bc * 128 * K;

  f32x4 acc[4][4];
  #pragma unroll
  for (int m = 0; m < 4; ++m)
    #pragma unroll
    for (int n = 0; n < 4; ++n) {
      f32x4 z = {0.f, 0.f, 0.f, 0.f};
      acc[m][n] = z;
    }

  const int nk = K >> 5;   // BK = 32
  int cur = 0;

  #pragma unroll
  for (int i = 0; i < 2; ++i) {
    int cg = (i * 4 + wave) * 64;
    int c  = cg + lane;
    int row = c >> 2, kc = c & 3;
    gload_lds16(Ag + (size_t)row * K + kc * 8, &lds[0][0][0] + cg * 8);
    gload_lds16(Bg + (size_t)row * K + kc * 8, &lds[0][1][0] + cg * 8);
  }
  __syncthreads();

  for (int ks = 0; ks < nk; ++ks) {
    if (ks + 1 < nk) {
      const bf16* Agk = Ag + (ks + 1) * 32;
      const bf16* Bgk = Bg + (ks + 1) * 32;
      #pragma unroll
      for (int i = 0; i < 2; ++i) {
        int cg = (i * 4 + wave) * 64;
        int c  = cg + lane;
        int row = c >> 2, kc = c & 3;
        gload_lds16(Agk + (size_t)row * K + kc * 8, &lds[cur ^ 1][0][0] + cg * 8);
        gload_lds16(Bgk + (size_t)row * K + kc * 8, &lds[cur ^ 1][1][0] + cg * 8);
      }
    }
    const bf16* lA = &lds[cur][0][0] + (wr * 64 + (lane & 15)) * 32 + (lane >> 4) * 8;
    const bf16* lB = &lds[cur][1][0] + (wc * 64 + (lane & 15)) * 32 + (lane >> 4) * 8;
    bf16x8 af[4], bfr[4];
    #pragma unroll
    for (int m = 0; m < 4; ++m) af[m]  = *(const bf16x8*)(lA + m * 512);
    #pragma unroll
    for (int n = 0; n < 4; ++n) bfr[n] = *(const bf16x8*)(lB + n * 512);
    #pragma unroll
    for (int m = 0; m < 4; ++m)
      #pragma unroll
      for (int n = 0; n < 4; ++n)
        acc[m][n] = __builtin_amdgcn_mfma_f32_16x16x32_bf16(af[m], bfr[n], acc[m][n], 0, 0, 0);
    __syncthreads();
    cur ^= 1;
  }

  const int rowbase0 = br * 128 + wr * 64 + ((lane >> 4) << 2);
  const int colbase  = bc * 128 + wc * 64 + (lane & 15);
  #pragma unroll
  for (int n = 0; n < 4; ++n) {
    int col = colbase + n * 16;
    float bv = bias[col];
    float tv = 0.f;
    if (MODE >= 1) tv = thr[col];
    #pragma unroll
    for (int m = 0; m < 4; ++m) {
      int row = rowbase0 + m * 16;
      #pragma unroll
      for (int j = 0; j < 4; ++j) {
        float v = acc[m][n][j] + bv;
        size_t off = (size_t)(row + j) * N + col;
        if (MODE == 0) {
          C[off] = (bf16)v;
        } else {
          float a = 1.f / (1.f + __expf(-v));
          if (MODE == 1) { C[off] = (bf16)a; Gate[off] = (a > tv) ? 1 : 0; }
          else           { Gate[off] = (a > tv) ? 1 : 0; }
        }
      }
    }
  }
}

// ======================= chunked linear scan =======================
// recurrence: h_t = (g_t ? d : 0) * h_{t-1} + z_t
// pass 1: per (chunk, lane-pair) compute A = prod(alpha), B = sum z*prod(alpha after)
__global__ __launch_bounds__(256)
void scan_p1(const bf16* __restrict__ Z, const unsigned char* __restrict__ G,
             const float* __restrict__ dr, float* __restrict__ Ab,
             float* __restrict__ Bb) {
  int idx = blockIdx.x * 256 + threadIdx.x;     // [0, CH*NE/2)
  int c  = idx >> 15;                           // chunk (NE/2 = 32768 pairs)
  int pe = idx & 32767;
  int e  = pe << 1;
  int h  = e & (HS_ - 1);
  float d0 = dr[h], d1 = dr[h + 1];
  float A0 = 1.f, A1 = 1.f, B0 = 0.f, B1 = 0.f;
  size_t base = (size_t)c * CL * NE + e;
  #pragma unroll 8
  for (int t = 0; t < CL; ++t, base += NE) {
    unsigned int zraw = *(const unsigned int*)(Z + base);
    unsigned short graw = *(const unsigned short*)(G + base);
    float z0 = __uint_as_float(zraw << 16);
    float z1 = __uint_as_float(zraw & 0xffff0000u);
    float a0 = (graw & 0x00ff) ? d0 : 0.f;
    float a1 = (graw & 0xff00) ? d1 : 0.f;
    B0 = B0 * a0 + z0;  A0 *= a0;
    B1 = B1 * a1 + z1;  A1 *= a1;
  }
  ((float2*)(Ab + ((size_t)c << 16)))[pe] = make_float2(A0, A1);
  ((float2*)(Bb + ((size_t)c << 16)))[pe] = make_float2(B0, B1);
}

// pass 2 (layer 1): sequentially combine chunks, store carry-in per chunk
__global__ __launch_bounds__(256)
void scan_p2(const float* __restrict__ Ab, const float* __restrict__ Bb,
             float* __restrict__ Hin) {
  int e = blockIdx.x * 256 + threadIdx.x;
  float h = 0.f;
  #pragma unroll
  for (int c = 0; c < CH; ++c) {
    size_t o = ((size_t)c << 16) + e;
    Hin[o] = h;
    h = Ab[o] * h + Bb[o];
  }
}

// pass 2 (layer 2): only the final state is needed -> an2 = tanh(h_final)
__global__ __launch_bounds__(256)
void scan_p2_final(const float* __restrict__ Ab, const float* __restrict__ Bb,
                   float* __restrict__ an2) {
  int e = blockIdx.x * 256 + threadIdx.x;
  float h = 0.f;
  #pragma unroll
  for (int c = 0; c < CH; ++c) {
    size_t o = ((size_t)c << 16) + e;
    h = Ab[o] * h + Bb[o];
  }
  an2[e] = ftanh(h);
}

// pass 3 (layer 1): replay chunk from carry-in, emit tanh(h) per step (in place ok)
__global__ __launch_bounds__(256)
void scan_p3(const bf16* __restrict__ Z, const unsigned char* __restrict__ G,
             const float* __restrict__ dr, const float* __restrict__ Hin,
             bf16* __restrict__ AN) {
  int idx = blockIdx.x * 256 + threadIdx.x;
  int c  = idx >> 15;
  int pe = idx & 32767;
  int e  = pe << 1;
  int h  = e & (HS_ - 1);
  float d0 = dr[h], d1 = dr[h + 1];
  float2 hin = ((const float2*)(Hin + ((size_t)c << 16)))[pe];
  float h0 = hin.x, h1 = hin.y;
  size_t base = (size_t)c * CL * NE + e;
  #pragma unroll 4
  for (int t = 0; t < CL; ++t, base += NE) {
    unsigned int zraw = *(const unsigned int*)(Z + base);
    unsigned short graw = *(const unsigned short*)(G + base);
    float z0 = __uint_as_float(zraw << 16);
    float z1 = __uint_as_float(zraw & 0xffff0000u);
    float a0 = (graw & 0x00ff) ? d0 : 0.f;
    float a1 = (graw & 0xff00) ? d1 : 0.f;
    h0 = h0 * a0 + z0;
    h1 = h1 * a1 + z1;
    bf16x2 o;
    o[0] = (bf16)ftanh(h0);
    o[1] = (bf16)ftanh(h1);
    *(bf16x2*)(AN + base) = o;
  }
}

// ---------------- readout: out[b,o] = sum_h an2[b,h] * W3[o,h] + b3[o] (fp32) -------
__global__ __launch_bounds__(256)
void readout(const float* __restrict__ an2, const float* __restrict__ W3,
             const float* __restrict__ b3, float* __restrict__ out) {
  int idx = blockIdx.x * 256 + threadIdx.x;
  int b = idx >> 9, o = idx & 511;
  const float4* a = (const float4*)(an2 + (size_t)b * HS_);
  const float4* w = (const float4*)(W3 + (size_t)o * HS_);
  float s = 0.f;
  #pragma unroll 4
  for (int k = 0; k < HS_ / 4; ++k) {
    float4 x = a[k], y = w[k];
    s += x.x * y.x + x.y * y.y + x.z * y.z + x.w * y.w;
  }
  out[idx] = s + b3[o];
}

extern "C" void kernel_launch(void* const* d_in, const int* in_sizes, int n_in,
                              void* d_out, int out_size, void* d_ws, size_t ws_size,
                              hipStream_t stream) {
  const float* data = (const float*)d_in[0];
  const float* W1   = (const float*)d_in[1];
  const float* b1   = (const float*)d_in[2];
  const float* Wi1  = (const float*)d_in[3];
  const float* bi1  = (const float*)d_in[4];
  const float* t1   = (const float*)d_in[5];
  const float* dr1  = (const float*)d_in[6];
  const float* W2   = (const float*)d_in[7];
  const float* b2   = (const float*)d_in[8];
  const float* Wi2  = (const float*)d_in[9];
  const float* bi2  = (const float*)d_in[10];
  const float* t2   = (const float*)d_in[11];
  const float* dr2  = (const float*)d_in[12];
  const float* W3   = (const float*)d_in[13];
  const float* b3   = (const float*)d_in[14];

  char* p = (char*)d_ws;
  bf16* Xbf  = (bf16*)p; p += (size_t)MROWS * INP_ * 2;   // 67 MB
  bf16* bufA = (bf16*)p; p += (size_t)MROWS * HS_ * 2;    // 134 MB  Z1 -> AN1 (in place)
  bf16* bufB = (bf16*)p; p += (size_t)MROWS * HS_ * 2;    // 134 MB  A1 -> Z2 (reused)
  unsigned char* G1 = (unsigned char*)p; p += (size_t)MROWS * HS_;  // 67 MB
  unsigned char* G2 = (unsigned char*)p; p += (size_t)MROWS * HS_;  // 67 MB
  bf16* W1b  = (bf16*)p; p += (size_t)HS_ * INP_ * 2;
  bf16* Wi1b = (bf16*)p; p += (size_t)HS_ * INP_ * 2;
  bf16* W2b  = (bf16*)p; p += (size_t)HS_ * HS_ * 2;
  bf16* Wi2b = (bf16*)p; p += (size_t)HS_ * HS_ * 2;
  float* an2 = (float*)p; p += (size_t)NE * 4;
  float* Ab  = (float*)p; p += (size_t)CH * NE * 4;       // 4 MB
  float* Bb  = (float*)p; p += (size_t)CH * NE * 4;       // 4 MB
  float* Hin = (float*)p; p += (size_t)CH * NE * 4;       // 4 MB

  // convert inputs/weights to bf16
  f2b<<<2048, 256, 0, stream>>>(data, Xbf, MROWS * INP_ / 4);
  f2b<<<512,  256, 0, stream>>>(W1,  W1b,  HS_ * INP_ / 4);
  f2b<<<512,  256, 0, stream>>>(Wi1, Wi1b, HS_ * INP_ / 4);
  f2b<<<1024, 256, 0, stream>>>(W2,  W2b,  HS_ * HS_ / 4);
  f2b<<<1024, 256, 0, stream>>>(Wi2, Wi2b, HS_ * HS_ / 4);

  const int nbn = HS_ / 128;                 // 8
  dim3 gg((MROWS / 128) * nbn);              // 4096 blocks

  // Z1 = X@W1^T + b1
  gemm_bt<0><<<gg, 256, 0, stream>>>(Xbf, W1b, b1, nullptr, bufA, nullptr, HS_, INP_, nbn);
  // A1 = sigmoid(X@Wi1^T + bi1), G1 = A1 > t1
  gemm_bt<1><<<gg, 256, 0, stream>>>(Xbf, Wi1b, bi1, t1, bufB, G1, HS_, INP_, nbn);
  // G2 = sigmoid(A1@Wi2^T + bi2) > t2
  gemm_bt<2><<<gg, 256, 0, stream>>>(bufB, Wi2b, bi2, t2, nullptr, G2, HS_, HS_, nbn);

  // --- layer-1 scan (chunked) ---
  scan_p1<<<CH * NE / 512, 256, 0, stream>>>(bufA, G1, dr1, Ab, Bb);
  scan_p2<<<NE / 256, 256, 0, stream>>>(Ab, Bb, Hin);
  scan_p3<<<CH * NE / 512, 256, 0, stream>>>(bufA, G1, dr1, Hin, bufA);

  // Z2 = AN1@W2^T + b2
  gemm_bt<0><<<gg, 256, 0, stream>>>(bufA, W2b, b2, nullptr, bufB, nullptr, HS_, HS_, nbn);

  // --- layer-2 scan (only final state) ---
  scan_p1<<<CH * NE / 512, 256, 0, stream>>>(bufB, G2, dr2, Ab, Bb);
  scan_p2_final<<<NE / 256, 256, 0, stream>>>(Ab, Bb, an2);

  // out = an2 @ W3^T + b3
  readout<<<BATCH * OUT_ / 256, 256, 0, stream>>>(an2, W3, b3, (float*)d_out);
}

// Round 5
// 1032.916 us; speedup vs baseline: 1.6534x; 1.0218x over previous
//
#include <hip/hip_runtime.h>
#include <hip/hip_bf16.h>

#define T_STEPS 1024
#define BATCH   64
#define INP_    512
#define HS_     1024
#define OUT_    512
#define MROWS   (T_STEPS*BATCH)   // 65536
#define NE      (BATCH*HS_)       // 65536 lanes in the recurrence
#define CH      16                // scan chunks
#define CL      (T_STEPS/CH)      // 64 steps per chunk

typedef __bf16 bf16;
typedef bf16  bf16x8 __attribute__((ext_vector_type(8)));
typedef bf16  bf16x4 __attribute__((ext_vector_type(4)));
typedef float f32x4  __attribute__((ext_vector_type(4)));

__device__ __forceinline__ void gload_lds16(const bf16* g, bf16* l) {
  __builtin_amdgcn_global_load_lds(
      (const __attribute__((address_space(1))) void*)g,
      (__attribute__((address_space(3))) void*)l,
      16, 0, 0);
}

__device__ __forceinline__ float ftanh(float x) {
  float e = __expf(2.f * x);
  return 1.f - 2.f / (e + 1.f);
}

// XCD-aware swizzle: same-A-panel tiles (consecutive bids) land on one XCD.
__device__ __forceinline__ int xcd_swizzle() {
  return (blockIdx.x & 7) * (gridDim.x >> 3) + (blockIdx.x >> 3);
}

// ---------------- fp32 -> bf16 conversion (vectorized x4) ----------------
__global__ void f2b(const float* __restrict__ in, bf16* __restrict__ out, int n4) {
  int stride = gridDim.x * blockDim.x;
  for (int i = blockIdx.x * blockDim.x + threadIdx.x; i < n4; i += stride) {
    float4 v = ((const float4*)in)[i];
    bf16x4 o;
    o[0] = (bf16)v.x; o[1] = (bf16)v.y; o[2] = (bf16)v.z; o[3] = (bf16)v.w;
    ((bf16x4*)out)[i] = o;
  }
}

// ============== GEMM core (128x128 tile, BK=32, gload_lds dbuf) ==============
#define GEMM_BODY(Ag, Bg, K)                                                     \
  __shared__ __align__(16) bf16 lds[2][2][128 * 32];                             \
  const int tid  = threadIdx.x;                                                  \
  const int wave = tid >> 6, lane = tid & 63;                                    \
  const int wr = wave >> 1, wc = wave & 1;                                       \
  f32x4 acc[4][4];                                                               \
  _Pragma("unroll")                                                              \
  for (int m = 0; m < 4; ++m)                                                    \
    _Pragma("unroll")                                                            \
    for (int n = 0; n < 4; ++n) { f32x4 z = {0.f,0.f,0.f,0.f}; acc[m][n] = z; }  \
  const int nk = (K) >> 5;                                                       \
  int cur = 0;                                                                   \
  _Pragma("unroll")                                                              \
  for (int i = 0; i < 2; ++i) {                                                  \
    int cg = (i * 4 + wave) * 64;                                                \
    int c  = cg + lane;                                                          \
    int row = c >> 2, kc = c & 3;                                                \
    gload_lds16(Ag + (size_t)row * (K) + kc * 8, &lds[0][0][0] + cg * 8);        \
    gload_lds16(Bg + (size_t)row * (K) + kc * 8, &lds[0][1][0] + cg * 8);        \
  }                                                                              \
  __syncthreads();                                                               \
  for (int ks = 0; ks < nk; ++ks) {                                              \
    if (ks + 1 < nk) {                                                           \
      const bf16* Agk = Ag + (ks + 1) * 32;                                      \
      const bf16* Bgk = Bg + (ks + 1) * 32;                                      \
      _Pragma("unroll")                                                          \
      for (int i = 0; i < 2; ++i) {                                              \
        int cg = (i * 4 + wave) * 64;                                            \
        int c  = cg + lane;                                                      \
        int row = c >> 2, kc = c & 3;                                            \
        gload_lds16(Agk + (size_t)row * (K) + kc * 8, &lds[cur^1][0][0] + cg*8); \
        gload_lds16(Bgk + (size_t)row * (K) + kc * 8, &lds[cur^1][1][0] + cg*8); \
      }                                                                          \
    }                                                                            \
    const bf16* lA = &lds[cur][0][0] + (wr * 64 + (lane & 15)) * 32 + (lane >> 4) * 8; \
    const bf16* lB = &lds[cur][1][0] + (wc * 64 + (lane & 15)) * 32 + (lane >> 4) * 8; \
    bf16x8 af[4], bfr[4];                                                        \
    _Pragma("unroll")                                                            \
    for (int m = 0; m < 4; ++m) af[m]  = *(const bf16x8*)(lA + m * 512);         \
    _Pragma("unroll")                                                            \
    for (int n = 0; n < 4; ++n) bfr[n] = *(const bf16x8*)(lB + n * 512);         \
    _Pragma("unroll")                                                            \
    for (int m = 0; m < 4; ++m)                                                  \
      _Pragma("unroll")                                                          \
      for (int n = 0; n < 4; ++n)                                                \
        acc[m][n] = __builtin_amdgcn_mfma_f32_16x16x32_bf16(af[m], bfr[n], acc[m][n], 0, 0, 0); \
    __syncthreads();                                                             \
    cur ^= 1;                                                                    \
  }

// ---------------- standard GEMM: MODE 0: C=acc+bias ; MODE 2: Gate=sigmoid(acc+bias)>thr ----
template<int MODE>
__global__ __launch_bounds__(256, 2)
void gemm_bt(const bf16* __restrict__ A, const bf16* __restrict__ Bw,
             const float* __restrict__ bias, const float* __restrict__ thr,
             bf16* __restrict__ C, unsigned char* __restrict__ Gate,
             int N, int K, int nbn) {
  const int bid = xcd_swizzle();
  const int br = bid / nbn, bc = bid % nbn;
  const bf16* Ag = A  + (size_t)br * 128 * K;
  const bf16* Bg = Bw + (size_t)bc * 128 * K;
  GEMM_BODY(Ag, Bg, K)

  const int rowbase0 = br * 128 + wr * 64 + ((lane >> 4) << 2);
  const int colbase  = bc * 128 + wc * 64 + (lane & 15);
  #pragma unroll
  for (int n = 0; n < 4; ++n) {
    int col = colbase + n * 16;
    float bv = bias[col];
    float tv = (MODE == 2) ? thr[col] : 0.f;
    #pragma unroll
    for (int m = 0; m < 4; ++m) {
      int row = rowbase0 + m * 16;
      #pragma unroll
      for (int j = 0; j < 4; ++j) {
        float v = acc[m][n][j] + bv;
        size_t off = (size_t)(row + j) * N + col;
        if (MODE == 0) {
          C[off] = (bf16)v;
        } else {
          float a = 1.f / (1.f + __expf(-v));
          Gate[off] = (a > tv) ? 1 : 0;
        }
      }
    }
  }
}

// ---------------- fused layer-1 GEMM: Wf=[W1;Wi1] (N=2048, K=512) -------------------
__global__ __launch_bounds__(256, 2)
void gemm_l1(const bf16* __restrict__ A, const bf16* __restrict__ Wf,
             const float* __restrict__ b1, const float* __restrict__ bi1,
             const float* __restrict__ t1,
             bf16* __restrict__ C0, bf16* __restrict__ C1,
             unsigned char* __restrict__ G1) {
  const int nbn = 16, K = INP_;
  const int bid = xcd_swizzle();
  const int br = bid / nbn, bc = bid % nbn;
  const bf16* Ag = A  + (size_t)br * 128 * K;
  const bf16* Bg = Wf + (size_t)bc * 128 * K;
  GEMM_BODY(Ag, Bg, K)

  const int rowbase0 = br * 128 + wr * 64 + ((lane >> 4) << 2);
  const int colbase  = bc * 128 + wc * 64 + (lane & 15);
  const bool inh = (bc >= 8);                      // whole block-tile is one half
  #pragma unroll
  for (int n = 0; n < 4; ++n) {
    int col = colbase + n * 16;
    int lc  = col & (HS_ - 1);
    float bv = inh ? bi1[lc] : b1[lc];
    float tv = inh ? t1[lc] : 0.f;
    #pragma unroll
    for (int m = 0; m < 4; ++m) {
      int row = rowbase0 + m * 16;
      #pragma unroll
      for (int j = 0; j < 4; ++j) {
        float v = acc[m][n][j] + bv;
        size_t off = (size_t)(row + j) * HS_ + lc;
        if (!inh) {
          C0[off] = (bf16)v;
        } else {
          float a = 1.f / (1.f + __expf(-v));
          C1[off] = (bf16)a;
          G1[off] = (a > tv) ? 1 : 0;
        }
      }
    }
  }
}

// ======================= chunked linear scan =======================
__global__ __launch_bounds__(256)
void scan_p1(const bf16* __restrict__ Z, const unsigned char* __restrict__ G,
             const float* __restrict__ dr, float* __restrict__ Ab,
             float* __restrict__ Bb) {
  int idx = blockIdx.x * 256 + threadIdx.x;     // [0, CH*NE/4)
  int c  = idx >> 14;                           // chunk (NE/4 = 16384 quads)
  int q  = idx & 16383;
  int e  = q << 2;
  int h  = e & (HS_ - 1);
  float d0 = dr[h], d1 = dr[h+1], d2 = dr[h+2], d3 = dr[h+3];
  float A0=1.f,A1=1.f,A2=1.f,A3=1.f, B0=0.f,B1=0.f,B2=0.f,B3=0.f;
  size_t base = (size_t)c * CL * NE + e;
  #pragma unroll 8
  for (int t = 0; t < CL; ++t, base += NE) {
    uint2 zr = *(const uint2*)(Z + base);
    unsigned int gr = *(const unsigned int*)(G + base);
    float z0 = __uint_as_float(zr.x << 16);
    float z1 = __uint_as_float(zr.x & 0xffff0000u);
    float z2 = __uint_as_float(zr.y << 16);
    float z3 = __uint_as_float(zr.y & 0xffff0000u);
    float a0 = (gr & 0x000000ffu) ? d0 : 0.f;
    float a1 = (gr & 0x0000ff00u) ? d1 : 0.f;
    float a2 = (gr & 0x00ff0000u) ? d2 : 0.f;
    float a3 = (gr & 0xff000000u) ? d3 : 0.f;
    B0 = B0*a0 + z0;  A0 *= a0;
    B1 = B1*a1 + z1;  A1 *= a1;
    B2 = B2*a2 + z2;  A2 *= a2;
    B3 = B3*a3 + z3;  A3 *= a3;
  }
  ((float4*)(Ab + ((size_t)c << 16)))[q] = make_float4(A0,A1,A2,A3);
  ((float4*)(Bb + ((size_t)c << 16)))[q] = make_float4(B0,B1,B2,B3);
}

__global__ __launch_bounds__(256)
void scan_p2(const float* __restrict__ Ab, const float* __restrict__ Bb,
             float* __restrict__ Hin) {
  int e = blockIdx.x * 256 + threadIdx.x;
  float h = 0.f;
  #pragma unroll
  for (int c = 0; c < CH; ++c) {
    size_t o = ((size_t)c << 16) + e;
    Hin[o] = h;
    h = Ab[o] * h + Bb[o];
  }
}

__global__ __launch_bounds__(256)
void scan_p2_final(const float* __restrict__ Ab, const float* __restrict__ Bb,
                   float* __restrict__ an2) {
  int e = blockIdx.x * 256 + threadIdx.x;
  float h = 0.f;
  #pragma unroll
  for (int c = 0; c < CH; ++c) {
    size_t o = ((size_t)c << 16) + e;
    h = Ab[o] * h + Bb[o];
  }
  an2[e] = ftanh(h);
}

__global__ __launch_bounds__(256)
void scan_p3(const bf16* __restrict__ Z, const unsigned char* __restrict__ G,
             const float* __restrict__ dr, const float* __restrict__ Hin,
             bf16* __restrict__ AN) {
  int idx = blockIdx.x * 256 + threadIdx.x;
  int c  = idx >> 14;
  int q  = idx & 16383;
  int e  = q << 2;
  int h  = e & (HS_ - 1);
  float d0 = dr[h], d1 = dr[h+1], d2 = dr[h+2], d3 = dr[h+3];
  float4 hin = ((const float4*)(Hin + ((size_t)c << 16)))[q];
  float h0 = hin.x, h1 = hin.y, h2 = hin.z, h3 = hin.w;
  size_t base = (size_t)c * CL * NE + e;
  #pragma unroll 4
  for (int t = 0; t < CL; ++t, base += NE) {
    uint2 zr = *(const uint2*)(Z + base);
    unsigned int gr = *(const unsigned int*)(G + base);
    float z0 = __uint_as_float(zr.x << 16);
    float z1 = __uint_as_float(zr.x & 0xffff0000u);
    float z2 = __uint_as_float(zr.y << 16);
    float z3 = __uint_as_float(zr.y & 0xffff0000u);
    h0 = h0 * ((gr & 0x000000ffu) ? d0 : 0.f) + z0;
    h1 = h1 * ((gr & 0x0000ff00u) ? d1 : 0.f) + z1;
    h2 = h2 * ((gr & 0x00ff0000u) ? d2 : 0.f) + z2;
    h3 = h3 * ((gr & 0xff000000u) ? d3 : 0.f) + z3;
    bf16x4 o;
    o[0] = (bf16)ftanh(h0);
    o[1] = (bf16)ftanh(h1);
    o[2] = (bf16)ftanh(h2);
    o[3] = (bf16)ftanh(h3);
    *(bf16x4*)(AN + base) = o;
  }
}

// ---------------- readout ----------------
__global__ __launch_bounds__(256)
void readout(const float* __restrict__ an2, const float* __restrict__ W3,
             const float* __restrict__ b3, float* __restrict__ out) {
  int idx = blockIdx.x * 256 + threadIdx.x;
  int b = idx >> 9, o = idx & 511;
  const float4* a = (const float4*)(an2 + (size_t)b * HS_);
  const float4* w = (const float4*)(W3 + (size_t)o * HS_);
  float s = 0.f;
  #pragma unroll 4
  for (int k = 0; k < HS_ / 4; ++k) {
    float4 x = a[k], y = w[k];
    s += x.x * y.x + x.y * y.y + x.z * y.z + x.w * y.w;
  }
  out[idx] = s + b3[o];
}

extern "C" void kernel_launch(void* const* d_in, const int* in_sizes, int n_in,
                              void* d_out, int out_size, void* d_ws, size_t ws_size,
                              hipStream_t stream) {
  const float* data = (const float*)d_in[0];
  const float* W1   = (const float*)d_in[1];
  const float* b1   = (const float*)d_in[2];
  const float* Wi1  = (const float*)d_in[3];
  const float* bi1  = (const float*)d_in[4];
  const float* t1   = (const float*)d_in[5];
  const float* dr1  = (const float*)d_in[6];
  const float* W2   = (const float*)d_in[7];
  const float* b2   = (const float*)d_in[8];
  const float* Wi2  = (const float*)d_in[9];
  const float* bi2  = (const float*)d_in[10];
  const float* t2   = (const float*)d_in[11];
  const float* dr2  = (const float*)d_in[12];
  const float* W3   = (const float*)d_in[13];
  const float* b3   = (const float*)d_in[14];

  char* p = (char*)d_ws;
  bf16* Xbf  = (bf16*)p; p += (size_t)MROWS * INP_ * 2;   // 67 MB
  bf16* bufA = (bf16*)p; p += (size_t)MROWS * HS_ * 2;    // 134 MB  Z1 -> AN1 (in place)
  bf16* bufB = (bf16*)p; p += (size_t)MROWS * HS_ * 2;    // 134 MB  A1 -> Z2 (reused)
  unsigned char* G1 = (unsigned char*)p; p += (size_t)MROWS * HS_;  // 67 MB
  unsigned char* G2 = (unsigned char*)p; p += (size_t)MROWS * HS_;  // 67 MB
  bf16* Wf   = (bf16*)p; p += (size_t)2 * HS_ * INP_ * 2; // [W1;Wi1] 2048x512
  bf16* W2b  = (bf16*)p; p += (size_t)HS_ * HS_ * 2;
  bf16* Wi2b = (bf16*)p; p += (size_t)HS_ * HS_ * 2;
  float* an2 = (float*)p; p += (size_t)NE * 4;
  float* Ab  = (float*)p; p += (size_t)CH * NE * 4;       // 4 MB
  float* Bb  = (float*)p; p += (size_t)CH * NE * 4;       // 4 MB
  float* Hin = (float*)p; p += (size_t)CH * NE * 4;       // 4 MB

  // convert inputs/weights to bf16 ([W1;Wi1] contiguous into Wf)
  f2b<<<2048, 256, 0, stream>>>(data, Xbf, MROWS * INP_ / 4);
  f2b<<<512,  256, 0, stream>>>(W1,  Wf,              HS_ * INP_ / 4);
  f2b<<<512,  256, 0, stream>>>(Wi1, Wf + HS_ * INP_, HS_ * INP_ / 4);
  f2b<<<1024, 256, 0, stream>>>(W2,  W2b,  HS_ * HS_ / 4);
  f2b<<<1024, 256, 0, stream>>>(Wi2, Wi2b, HS_ * HS_ / 4);

  // fused layer-1 GEMM: Z1 -> bufA, A1 -> bufB, G1
  gemm_l1<<<dim3((MROWS / 128) * 16), 256, 0, stream>>>(Xbf, Wf, b1, bi1, t1, bufA, bufB, G1);

  const int nbn = HS_ / 128;                 // 8
  dim3 gg((MROWS / 128) * nbn);              // 4096 blocks

  // G2 = sigmoid(A1@Wi2^T + bi2) > t2
  gemm_bt<2><<<gg, 256, 0, stream>>>(bufB, Wi2b, bi2, t2, nullptr, G2, HS_, HS_, nbn);

  // --- layer-1 scan (chunked) ---
  scan_p1<<<CH * NE / 1024, 256, 0, stream>>>(bufA, G1, dr1, Ab, Bb);
  scan_p2<<<NE / 256, 256, 0, stream>>>(Ab, Bb, Hin);
  scan_p3<<<CH * NE / 1024, 256, 0, stream>>>(bufA, G1, dr1, Hin, bufA);

  // Z2 = AN1@W2^T + b2
  gemm_bt<0><<<gg, 256, 0, stream>>>(bufA, W2b, b2, nullptr, bufB, nullptr, HS_, HS_, nbn);

  // --- layer-2 scan (only final state) ---
  scan_p1<<<CH * NE / 1024, 256, 0, stream>>>(bufB, G2, dr2, Ab, Bb);
  scan_p2_final<<<NE / 256, 256, 0, stream>>>(Ab, Bb, an2);

  // out = an2 @ W3^T + b3
  readout<<<BATCH * OUT_ / 256, 256, 0, stream>>>(an2, W3, b3, (float*)d_out);
}